// Round 1
// baseline (665.703 us; speedup 1.0000x reference)
//
#include <hip/hip_runtime.h>

#define NN 8192     // nodes
#define DIM 256     // feature dim
#define BATCH 4096  // batch
#define PT 32       // rows per agg block
#define JS 8        // j-split
#define KJ 32       // j chunk staged in LDS

// ---------------- zero workspace region (rowsum + h0), 1052672 floats ----------------
__global__ void zero_kernel(float4* __restrict__ p) {
    p[blockIdx.x * 256 + threadIdx.x] = make_float4(0.f, 0.f, 0.f, 0.f);
}

// ---------------- stable partition: positives first, order preserved ----------------
__global__ void scan_kernel(const int* __restrict__ labels,
                            const int* __restrict__ nodeidx,
                            float* __restrict__ out_labels,
                            int* __restrict__ idx_sorted,
                            int* __restrict__ Pp) {
    __shared__ int s[256];
    int t = threadIdx.x;
    int base = t * 16;
    int l[16];
    int cnt = 0;
#pragma unroll
    for (int k = 0; k < 16; ++k) { l[k] = labels[base + k]; cnt += l[k]; }
    s[t] = cnt;
    __syncthreads();
    for (int off = 1; off < 256; off <<= 1) {
        int v = (t >= off) ? s[t - off] : 0;
        __syncthreads();
        s[t] += v;
        __syncthreads();
    }
    int P = s[255];               // total positives
    int ones_excl = s[t] - cnt;   // ones before this thread's chunk
#pragma unroll
    for (int k = 0; k < 16; ++k) {
        int i = base + k;
        int pos;
        if (l[k]) { pos = ones_excl; ones_excl++; }
        else      { pos = P + (i - ones_excl); }
        out_labels[pos] = l[k] ? 1.0f : 0.0f;
        idx_sorted[pos] = nodeidx[i];
    }
    if (t == 0) *Pp = P;
}

// ---------------- row sums of gathered A rows (positives only) ----------------
__global__ void rowsum_kernel(const float* __restrict__ A,
                              const int* __restrict__ idx_sorted,
                              const int* __restrict__ Pp,
                              float* __restrict__ rowsum) {
    int r = blockIdx.x;
    if (r >= *Pp) return;
    long row = idx_sorted[r];
    const float4* Ar = (const float4*)(A + row * (long)NN);
    float s = 0.f;
#pragma unroll
    for (int it = 0; it < 8; ++it) {
        float4 v = Ar[threadIdx.x + it * 256];
        s += (v.x + v.y) + (v.z + v.w);
    }
#pragma unroll
    for (int off = 32; off > 0; off >>= 1) s += __shfl_down(s, off, 64);
    __shared__ float ws4[4];
    int lane = threadIdx.x & 63, wv = threadIdx.x >> 6;
    if (lane == 0) ws4[wv] = s;
    __syncthreads();
    if (threadIdx.x == 0) rowsum[r] = (ws4[0] + ws4[1]) + (ws4[2] + ws4[3]);
}

// ---------------- gathered GEMM: h0[r,:] += A[idx[r], jchunk] @ E[jchunk, :] ----------------
// grid (JS, BATCH/PT), 256 threads. Thread tile: 4 rows x 8 cols. Atomic accumulate.
__global__ void agg_kernel(const float* __restrict__ A,
                           const float* __restrict__ E,
                           const int* __restrict__ idx_sorted,
                           const int* __restrict__ Pp,
                           float* __restrict__ h0) {
    __shared__ float At[KJ][36];    // [jj][p], padded: staging-write conflict-light, b128-aligned reads
    __shared__ float Et[KJ][DIM];   // [jj][d]
    __shared__ int rows[PT];
    int P = *Pp;
    int r0 = blockIdx.y * PT;
    if (r0 >= P) return;            // uniform exit, no barrier hazard
    int t = threadIdx.x;
    if (t < PT) rows[t] = (r0 + t < P) ? idx_sorted[r0 + t] : -1;
    int td = t & 31, tp = t >> 5;   // cols d = td*8..+7, rows p = tp*4..+3
    float acc[4][8];
#pragma unroll
    for (int i = 0; i < 4; ++i)
#pragma unroll
        for (int k = 0; k < 8; ++k) acc[i][k] = 0.f;

    const int jspan = NN / JS;             // 1024
    const int j0base = blockIdx.x * jspan;
    for (int c = 0; c < jspan / KJ; ++c) { // 32 chunks
        int j0 = j0base + c * KJ;
        __syncthreads();  // also covers rows[] availability on c==0
        // stage A: 32 gathered rows x 32 j, transposed into At[jj][p]
#pragma unroll
        for (int it = 0; it < 4; ++it) {
            int idx = it * 256 + t;
            int p = idx >> 5, jj = idx & 31;
            int row = rows[p];
            At[jj][p] = (row >= 0) ? A[(long)row * NN + j0 + jj] : 0.f;
        }
        // stage E: 32 j x 256 d (float4, coalesced)
#pragma unroll
        for (int it = 0; it < 8; ++it) {
            int idx = it * 256 + t;
            int j = idx >> 6, dq = idx & 63;
            *(float4*)&Et[j][dq * 4] =
                *(const float4*)(E + (long)(j0 + j) * DIM + dq * 4);
        }
        __syncthreads();
#pragma unroll
        for (int jj = 0; jj < KJ; ++jj) {
            float4 a  = *(const float4*)&At[jj][tp * 4];
            float4 e0 = *(const float4*)&Et[jj][td * 8];
            float4 e1 = *(const float4*)&Et[jj][td * 8 + 4];
            float av[4] = {a.x, a.y, a.z, a.w};
            float ev[8] = {e0.x, e0.y, e0.z, e0.w, e1.x, e1.y, e1.z, e1.w};
#pragma unroll
            for (int i = 0; i < 4; ++i)
#pragma unroll
                for (int k = 0; k < 8; ++k)
                    acc[i][k] = fmaf(av[i], ev[k], acc[i][k]);
        }
    }
#pragma unroll
    for (int i = 0; i < 4; ++i) {
        long r = r0 + tp * 4 + i;
#pragma unroll
        for (int k = 0; k < 8; ++k)
            atomicAdd(&h0[r * DIM + td * 8 + k], acc[i][k]);
    }
}

// ---------------- finalize h0: normalize positives, direct-copy negatives ----------------
__global__ void finalize_kernel(const float* __restrict__ E,
                                const int* __restrict__ idx_sorted,
                                const int* __restrict__ Pp,
                                const float* __restrict__ rowsum,
                                float* __restrict__ h0) {
    int r = blockIdx.x, d = threadIdx.x;
    if (r < *Pp) h0[(long)r * DIM + d] *= (1.0f / rowsum[r]);
    else         h0[(long)r * DIM + d] = E[(long)idx_sorted[r] * DIM + d];
}

// ---------------- dense layer: Out = relu(In @ W^T + b), 64x64 tiles ----------------
__global__ void layer_kernel(const float* __restrict__ In,
                             const float* __restrict__ W,
                             const float* __restrict__ bias,
                             float* __restrict__ Out) {
    __shared__ float Ht[32][68];  // [kk][r], padded for staging; 272B row stride keeps b128 aligned
    __shared__ float Wt[32][68];  // [kk][c]
    int t = threadIdx.x;
    int tc = t & 15, tr = t >> 4;
    int r0 = blockIdx.x * 64, c0 = blockIdx.y * 64;
    float acc[4][4];
#pragma unroll
    for (int i = 0; i < 4; ++i)
#pragma unroll
        for (int j = 0; j < 4; ++j) acc[i][j] = 0.f;

    for (int k0 = 0; k0 < DIM; k0 += 32) {
        __syncthreads();
#pragma unroll
        for (int it = 0; it < 8; ++it) {
            int idx = it * 256 + t;
            int r = idx >> 5, kk = idx & 31;
            Ht[kk][r] = In[(long)(r0 + r) * DIM + k0 + kk];
            Wt[kk][r] = W[(long)(c0 + r) * DIM + k0 + kk];
        }
        __syncthreads();
#pragma unroll
        for (int kk = 0; kk < 32; ++kk) {
            float4 a  = *(const float4*)&Ht[kk][tr * 4];
            float4 bv = *(const float4*)&Wt[kk][tc * 4];
            float av[4] = {a.x, a.y, a.z, a.w};
            float bw[4] = {bv.x, bv.y, bv.z, bv.w};
#pragma unroll
            for (int i = 0; i < 4; ++i)
#pragma unroll
                for (int j = 0; j < 4; ++j)
                    acc[i][j] = fmaf(av[i], bw[j], acc[i][j]);
        }
    }
#pragma unroll
    for (int j = 0; j < 4; ++j) {
        float bj = bias[c0 + tc * 4 + j];
#pragma unroll
        for (int i = 0; i < 4; ++i) {
            float v = acc[i][j] + bj;
            Out[(long)(r0 + tr * 4 + i) * DIM + c0 + tc * 4 + j] = v > 0.f ? v : 0.f;
        }
    }
}

extern "C" void kernel_launch(void* const* d_in, const int* in_sizes, int n_in,
                              void* d_out, int out_size, void* d_ws, size_t ws_size,
                              hipStream_t stream) {
    const int*   labels  = (const int*)d_in[0];
    const int*   nodeidx = (const int*)d_in[1];
    const float* A       = (const float*)d_in[2];
    const float* E       = (const float*)d_in[3];
    const float* W       = (const float*)d_in[4];
    const float* bias    = (const float*)d_in[5];
    float* out = (float*)d_out;   // [0,B): labels_sorted (as float); [B, B+B*D): h

    // ws layout (float elements):
    // [0,4096) idx_sorted (int), [4096] P (int), pad to 4352,
    // [4352,8448) rowsum, [8448, 8448+1M) h0, then h1
    int*   idx_sorted = (int*)d_ws;
    int*   Pp         = idx_sorted + BATCH;
    float* rowsum     = (float*)d_ws + 4352;
    float* h0         = (float*)d_ws + 8448;
    float* h1         = h0 + (long)BATCH * DIM;

    // zero rowsum + h0 (contiguous: 4096 + 1048576 = 1052672 floats = 263168 float4)
    zero_kernel<<<dim3(1028), dim3(256), 0, stream>>>((float4*)rowsum);
    scan_kernel<<<dim3(1), dim3(256), 0, stream>>>(labels, nodeidx, out, idx_sorted, Pp);
    rowsum_kernel<<<dim3(BATCH), dim3(256), 0, stream>>>(A, idx_sorted, Pp, rowsum);
    agg_kernel<<<dim3(JS, BATCH / PT), dim3(256), 0, stream>>>(A, E, idx_sorted, Pp, h0);
    finalize_kernel<<<dim3(BATCH), dim3(256), 0, stream>>>(E, idx_sorted, Pp, rowsum, h0);
    layer_kernel<<<dim3(64, 4), dim3(256), 0, stream>>>(h0, W,          bias,       h1);
    layer_kernel<<<dim3(64, 4), dim3(256), 0, stream>>>(h1, W + 65536,  bias + 256, h0);
    layer_kernel<<<dim3(64, 4), dim3(256), 0, stream>>>(h0, W + 131072, bias + 512, out + BATCH);
}

// Round 3
// 474.595 us; speedup vs baseline: 1.4027x; 1.4027x over previous
//
#include <hip/hip_runtime.h>

#define NN 8192     // nodes
#define DIM 256     // feature dim
#define BATCH 4096  // batch
#define KS 16       // k-splits in agg
#define KSPAN 512   // NN/KS
#define NCH 16      // KSPAN/32 chunks per block

typedef __attribute__((ext_vector_type(8))) short bh8;
typedef __attribute__((ext_vector_type(4))) float f32x4;

__device__ __forceinline__ unsigned short f2b(float f) {
    unsigned int u = __builtin_bit_cast(unsigned int, f);
    u += 0x7fffu + ((u >> 16) & 1u);   // RNE
    return (unsigned short)(u >> 16);
}
__device__ __forceinline__ bh8 pack8(float4 x, float4 y) {
    bh8 v;
    v[0] = (short)f2b(x.x); v[1] = (short)f2b(x.y);
    v[2] = (short)f2b(x.z); v[3] = (short)f2b(x.w);
    v[4] = (short)f2b(y.x); v[5] = (short)f2b(y.y);
    v[6] = (short)f2b(y.z); v[7] = (short)f2b(y.w);
    return v;
}

// ---------------- zero h0 (4 MB) ----------------
__global__ void zero_kernel(float4* __restrict__ p) {
    p[blockIdx.x * 256 + threadIdx.x] = make_float4(0.f, 0.f, 0.f, 0.f);
}

// ---------------- stable partition: positives first ----------------
__global__ void scan_kernel(const int* __restrict__ labels,
                            const int* __restrict__ nodeidx,
                            float* __restrict__ out_labels,
                            int* __restrict__ idx_sorted,
                            int* __restrict__ Pp) {
    __shared__ int s[256];
    int t = threadIdx.x;
    int base = t * 16;
    int l[16];
    int cnt = 0;
#pragma unroll
    for (int k = 0; k < 16; ++k) { l[k] = labels[base + k]; cnt += l[k]; }
    s[t] = cnt;
    __syncthreads();
    for (int off = 1; off < 256; off <<= 1) {
        int v = (t >= off) ? s[t - off] : 0;
        __syncthreads();
        s[t] += v;
        __syncthreads();
    }
    int P = s[255];
    int ones_excl = s[t] - cnt;
#pragma unroll
    for (int k = 0; k < 16; ++k) {
        int i = base + k;
        int pos;
        if (l[k]) { pos = ones_excl; ones_excl++; }
        else      { pos = P + (i - ones_excl); }
        out_labels[pos] = l[k] ? 1.0f : 0.0f;
        idx_sorted[pos] = nodeidx[i];
    }
    if (t == 0) *Pp = P;
}

// ---------------- row sums of gathered A rows (positives only) ----------------
__global__ void rowsum_kernel(const float* __restrict__ A,
                              const int* __restrict__ idx_sorted,
                              const int* __restrict__ Pp,
                              float* __restrict__ rowsum) {
    int r = blockIdx.x;
    if (r >= *Pp) return;
    long row = idx_sorted[r];
    const float4* Ar = (const float4*)(A + row * (long)NN);
    float s = 0.f;
#pragma unroll
    for (int it = 0; it < 8; ++it) {
        float4 v = Ar[threadIdx.x + it * 256];
        s += (v.x + v.y) + (v.z + v.w);
    }
#pragma unroll
    for (int off = 32; off > 0; off >>= 1) s += __shfl_down(s, off, 64);
    __shared__ float ws4[4];
    int lane = threadIdx.x & 63, wv = threadIdx.x >> 6;
    if (lane == 0) ws4[wv] = s;
    __syncthreads();
    if (threadIdx.x == 0) rowsum[r] = (ws4[0] + ws4[1]) + (ws4[2] + ws4[3]);
}

// ---------------- E -> E^T bf16 [DIM][NN] ----------------
__global__ void cvtE_kernel(const float* __restrict__ E, unsigned short* __restrict__ Ebt) {
    int k0 = blockIdx.x * 32;
    int c = threadIdx.x;
    float v[32];
#pragma unroll
    for (int kk = 0; kk < 32; ++kk) v[kk] = E[(long)(k0 + kk) * DIM + c];
    unsigned short u[32];
#pragma unroll
    for (int kk = 0; kk < 32; ++kk) u[kk] = f2b(v[kk]);
    uint4* dst = (uint4*)(Ebt + (long)c * NN + k0);
#pragma unroll
    for (int q = 0; q < 4; ++q) {
        uint4 w;
        w.x = u[q*8+0] | ((unsigned)u[q*8+1] << 16);
        w.y = u[q*8+2] | ((unsigned)u[q*8+3] << 16);
        w.z = u[q*8+4] | ((unsigned)u[q*8+5] << 16);
        w.w = u[q*8+6] | ((unsigned)u[q*8+7] << 16);
        dst[q] = w;
    }
}

// ---------------- agg MFMA: h0[r,:] += A[idx[r],:] @ E  (unnormalized) ----------------
// grid (KS, 2, BATCH/64), 256 thr = 4 waves. Wave w: rows [r0+w*16, +16),
// cols [ns*128, +128) = 8 n-frags. LDS-free: A frags fp32->bf16 in-register,
// B frags 16B direct from bf16 E^T (L2-hot). fp32 atomic accumulate.
// Rows >= P compute garbage; finalize overwrites them (direct assign).
__global__ void agg_kernel(const float* __restrict__ A,
                           const unsigned short* __restrict__ Ebt,
                           const int* __restrict__ idx_sorted,
                           const int* __restrict__ Pp,
                           float* __restrict__ h0) {
    int P = *Pp;
    int r0 = blockIdx.z * 64;
    if (r0 >= P) return;
    int t = threadIdx.x, l = t & 63, w = t >> 6;
    long kbase = (long)blockIdx.x * KSPAN;
    int c0 = blockIdx.y * 128;
    int r = r0 + w * 16 + (l & 15);
    long arow = (long)idx_sorted[r] * NN;
    int ko = (l >> 4) * 8;
    const unsigned short* eb = Ebt + (long)(c0 + (l & 15)) * NN + kbase + ko;

    f32x4 acc[8];
#pragma unroll
    for (int nb = 0; nb < 8; ++nb) acc[nb] = (f32x4){0.f, 0.f, 0.f, 0.f};

    for (int ch = 0; ch < NCH; ++ch) {
        long k = kbase + ch * 32 + ko;
        float4 x = *(const float4*)(A + arow + k);
        float4 y = *(const float4*)(A + arow + k + 4);
        bh8 a = pack8(x, y);
#pragma unroll
        for (int nb = 0; nb < 8; ++nb) {
            bh8 b = *(const bh8*)(eb + (long)nb * 16 * NN + ch * 32);
            acc[nb] = __builtin_amdgcn_mfma_f32_16x16x32_bf16(a, b, acc[nb], 0, 0, 0);
        }
    }
    int colb = c0 + (l & 15);
    int rb = r0 + w * 16 + (l >> 4) * 4;
#pragma unroll
    for (int nb = 0; nb < 8; ++nb)
#pragma unroll
        for (int j = 0; j < 4; ++j)
            atomicAdd(&h0[(long)(rb + j) * DIM + colb + nb * 16], acc[nb][j]);
}

// ---------------- finalize: scale positives by 1/rowsum, copy negatives exact fp32 ----------------
__global__ void finalize_kernel(const float* __restrict__ E,
                                const int* __restrict__ idx_sorted,
                                const int* __restrict__ Pp,
                                const float* __restrict__ rowsum,
                                float* __restrict__ h0) {
    int r = blockIdx.x, d = threadIdx.x;
    if (r < *Pp) h0[(long)r * DIM + d] *= (1.0f / rowsum[r]);
    else         h0[(long)r * DIM + d] = E[(long)idx_sorted[r] * DIM + d];
}

// ---------------- layer: Out = relu(In @ W^T + b), bf16 MFMA, fp32 in/out ----------------
// grid (64, 4), 256 thr = 4 waves; wave w: rows [r0+w*16,+16) x cols [c0,+64).
// W is [out][in] row-major == exactly the MFMA B-frag layout; cvt on load.
__global__ void layer_kernel(const float* __restrict__ In,
                             const float* __restrict__ W,
                             const float* __restrict__ bias,
                             float* __restrict__ Out) {
    int t = threadIdx.x, l = t & 63, w = t >> 6;
    int r0 = blockIdx.x * 64, c0 = blockIdx.y * 64;
    int rloc = r0 + w * 16 + (l & 15);
    int ko = (l >> 4) * 8;
    f32x4 acc[4];
#pragma unroll
    for (int nb = 0; nb < 4; ++nb) acc[nb] = (f32x4){0.f, 0.f, 0.f, 0.f};

#pragma unroll
    for (int ch = 0; ch < 8; ++ch) {
        int k = ch * 32 + ko;
        const float* ip = In + (long)rloc * DIM + k;
        bh8 a = pack8(*(const float4*)ip, *(const float4*)(ip + 4));
#pragma unroll
        for (int nb = 0; nb < 4; ++nb) {
            const float* wp = W + (long)(c0 + nb * 16 + (l & 15)) * DIM + k;
            bh8 b = pack8(*(const float4*)wp, *(const float4*)(wp + 4));
            acc[nb] = __builtin_amdgcn_mfma_f32_16x16x32_bf16(a, b, acc[nb], 0, 0, 0);
        }
    }
    int rbase = r0 + w * 16 + (l >> 4) * 4;
#pragma unroll
    for (int nb = 0; nb < 4; ++nb) {
        int col = c0 + nb * 16 + (l & 15);
        float bj = bias[col];
#pragma unroll
        for (int j = 0; j < 4; ++j) {
            float v = acc[nb][j] + bj;
            Out[(long)(rbase + j) * DIM + col] = v > 0.f ? v : 0.f;
        }
    }
}

extern "C" void kernel_launch(void* const* d_in, const int* in_sizes, int n_in,
                              void* d_out, int out_size, void* d_ws, size_t ws_size,
                              hipStream_t stream) {
    const int*   labels  = (const int*)d_in[0];
    const int*   nodeidx = (const int*)d_in[1];
    const float* A       = (const float*)d_in[2];
    const float* E       = (const float*)d_in[3];
    const float* W       = (const float*)d_in[4];
    const float* bias    = (const float*)d_in[5];
    float* out = (float*)d_out;   // [0,B): labels_sorted as float; [B, B+B*D): h

    // ws layout (float offsets):
    //   0        idx_sorted int[4096]
    //   4096     P (int)
    //   4352     rowsum float[4096]
    //   8448     h0  float[1048576] (4 MB)
    //   1057024  h1  float[1048576] (4 MB)
    //   2105600  Ebt bf16[2097152]  (4 MB)
    int*            idx_sorted = (int*)d_ws;
    int*            Pp         = idx_sorted + BATCH;
    float*          rowsum     = (float*)d_ws + 4352;
    float*          h0         = (float*)d_ws + 8448;
    float*          h1         = (float*)d_ws + 1057024;
    unsigned short* Ebt        = (unsigned short*)((float*)d_ws + 2105600);

    zero_kernel<<<dim3(1024), dim3(256), 0, stream>>>((float4*)h0);
    scan_kernel<<<dim3(1), dim3(256), 0, stream>>>(labels, nodeidx, out, idx_sorted, Pp);
    rowsum_kernel<<<dim3(BATCH), dim3(256), 0, stream>>>(A, idx_sorted, Pp, rowsum);
    cvtE_kernel<<<dim3(NN / 32), dim3(256), 0, stream>>>(E, Ebt);
    agg_kernel<<<dim3(KS, 2, BATCH / 64), dim3(256), 0, stream>>>(A, Ebt, idx_sorted, Pp, h0);
    finalize_kernel<<<dim3(BATCH), dim3(256), 0, stream>>>(E, idx_sorted, Pp, rowsum, h0);
    layer_kernel<<<dim3(64, 4), dim3(256), 0, stream>>>(h0, W,          bias,       h1);
    layer_kernel<<<dim3(64, 4), dim3(256), 0, stream>>>(h1, W + 65536,  bias + 256, h0);
    layer_kernel<<<dim3(64, 4), dim3(256), 0, stream>>>(h0, W + 131072, bias + 512, out + BATCH);
}